// Round 1
// baseline (2849.558 us; speedup 1.0000x reference)
//
#include <hip/hip_runtime.h>
#include <hip/hip_bf16.h>

#define N_NODES 100000
#define N_EDGES 1600000
#define D 128

// ---------------------------------------------------------------------------
// GEMM: support[n][j] = sum_k x[n][k] * W[k][j] + lin_bias[j]
// Tile: 64 rows x 64 cols per block, 256 threads, 4x4 micro-tile per thread.
// LDS: W half (128x64 = 32 KB) + x tile transposed (128x64 = 32 KB) = 64 KB.
// ---------------------------------------------------------------------------
__global__ __launch_bounds__(256) void gemm_kernel(
    const float* __restrict__ x, const float* __restrict__ W,
    const float* __restrict__ lin_bias, float* __restrict__ support) {
  __shared__ float Wl[128 * 64];   // [k][c] c in 0..63 (this block's col half)
  __shared__ float xt[128 * 64];   // [k][r] r in 0..63 (transposed x tile)

  const int t = threadIdx.x;
  const int bx = blockIdx.x >> 1;        // row-tile index
  const int cy = blockIdx.x & 1;         // col half
  const int row0 = bx * 64;
  const int col0 = cy * 64;

  // Stage W[:, col0:col0+64]: 128*16 float4 loads, coalesced per 16 lanes.
  for (int i = t; i < 128 * 16; i += 256) {
    const int k = i >> 4, c4 = i & 15;
    float4 w4 = *(const float4*)(W + (size_t)k * D + col0 + 4 * c4);
    ((float4*)Wl)[k * 16 + c4] = w4;
  }
  // Stage x rows row0..row0+63 transposed into xt[k][r].
  for (int i = t; i < 64 * 32; i += 256) {
    const int r = i & 63, kc = i >> 6;   // kc: which float4 chunk of k
    float4 v = make_float4(0.f, 0.f, 0.f, 0.f);
    const int row = row0 + r;
    if (row < N_NODES) v = *(const float4*)(x + (size_t)row * D + 4 * kc);
    xt[(4 * kc + 0) * 64 + r] = v.x;
    xt[(4 * kc + 1) * 64 + r] = v.y;
    xt[(4 * kc + 2) * 64 + r] = v.z;
    xt[(4 * kc + 3) * 64 + r] = v.w;
  }
  __syncthreads();

  const int cg = t & 15;    // col group: cols col0 + 4*cg .. +3
  const int rg = t >> 4;    // row group: rows row0 + 4*rg .. +3
  const float4* Wl4 = (const float4*)Wl;
  const float4* xt4 = (const float4*)xt;

  float acc[4][4];
#pragma unroll
  for (int i = 0; i < 4; ++i)
#pragma unroll
    for (int j = 0; j < 4; ++j) acc[i][j] = 0.f;

#pragma unroll 16
  for (int k = 0; k < 128; ++k) {
    const float4 wv = Wl4[k * 16 + cg];
    const float4 xv = xt4[k * 16 + rg];
    acc[0][0] += xv.x * wv.x; acc[0][1] += xv.x * wv.y;
    acc[0][2] += xv.x * wv.z; acc[0][3] += xv.x * wv.w;
    acc[1][0] += xv.y * wv.x; acc[1][1] += xv.y * wv.y;
    acc[1][2] += xv.y * wv.z; acc[1][3] += xv.y * wv.w;
    acc[2][0] += xv.z * wv.x; acc[2][1] += xv.z * wv.y;
    acc[2][2] += xv.z * wv.z; acc[2][3] += xv.z * wv.w;
    acc[3][0] += xv.w * wv.x; acc[3][1] += xv.w * wv.y;
    acc[3][2] += xv.w * wv.z; acc[3][3] += xv.w * wv.w;
  }

  const float4 lb = *(const float4*)(lin_bias + col0 + 4 * cg);
#pragma unroll
  for (int i = 0; i < 4; ++i) {
    const int row = row0 + 4 * rg + i;
    if (row < N_NODES) {
      float4 o;
      o.x = acc[i][0] + lb.x; o.y = acc[i][1] + lb.y;
      o.z = acc[i][2] + lb.z; o.w = acc[i][3] + lb.w;
      *(float4*)(support + (size_t)row * D + col0 + 4 * cg) = o;
    }
  }
}

// ---------------------------------------------------------------------------
// Init out[r][j] = bias[j]  (d_out is poisoned 0xAA before every launch)
// ---------------------------------------------------------------------------
__global__ __launch_bounds__(256) void init_out_kernel(
    const float* __restrict__ bias, float* __restrict__ out) {
  const size_t idx = (size_t)blockIdx.x * 256 + threadIdx.x;  // float4 index
  const float4 b = ((const float4*)bias)[idx & 31];
  ((float4*)out)[idx] = b;
}

// ---------------------------------------------------------------------------
// Scatter: for each edge e, out[rows[e]] += vals[e] * support[cols[e]]
// 32 threads per edge, float4 per thread, scalar f32 atomics.
// ---------------------------------------------------------------------------
__global__ __launch_bounds__(256) void scatter_kernel(
    const int* __restrict__ rows, const int* __restrict__ cols,
    const float* __restrict__ vals, const float* __restrict__ support,
    float* __restrict__ out) {
  const size_t tid = (size_t)blockIdx.x * 256 + threadIdx.x;
  const int e = (int)(tid >> 5);
  const int q = (int)(tid & 31);

  const int r = rows[e];
  const int c = cols[e];
  const float v = vals[e];

  const float4 s4 = ((const float4*)support)[(size_t)c * 32 + q];
  float* o = out + (size_t)r * D + 4 * q;
  atomicAdd(o + 0, v * s4.x);
  atomicAdd(o + 1, v * s4.y);
  atomicAdd(o + 2, v * s4.z);
  atomicAdd(o + 3, v * s4.w);
}

extern "C" void kernel_launch(void* const* d_in, const int* in_sizes, int n_in,
                              void* d_out, int out_size, void* d_ws, size_t ws_size,
                              hipStream_t stream) {
  const float* x        = (const float*)d_in[0];
  const float* W        = (const float*)d_in[1];
  const float* lin_bias = (const float*)d_in[2];
  const float* bias     = (const float*)d_in[3];
  const int*   adj_rows = (const int*)d_in[4];
  const int*   adj_cols = (const int*)d_in[5];
  const float* adj_vals = (const float*)d_in[6];
  float* out = (float*)d_out;
  float* support = (float*)d_ws;  // N_NODES * D floats = 51.2 MB

  // GEMM: 1563 row tiles (64 rows each, covers 100032 >= 100000) x 2 col halves
  gemm_kernel<<<1563 * 2, 256, 0, stream>>>(x, W, lin_bias, support);

  // Init out with bias: 100000*128/4 float4 / 256 = 12500 blocks (exact)
  init_out_kernel<<<12500, 256, 0, stream>>>(bias, out);

  // Scatter: 1.6M edges * 32 threads = 51.2M threads / 256 = 200000 blocks (exact)
  scatter_kernel<<<200000, 256, 0, stream>>>(adj_rows, adj_cols, adj_vals,
                                             support, out);
}

// Round 2
// 729.013 us; speedup vs baseline: 3.9088x; 3.9088x over previous
//
#include <hip/hip_runtime.h>
#include <hip/hip_bf16.h>

#define N_NODES 100000
#define N_EDGES 1600000
#define D 128

// ---------------------------------------------------------------------------
// GEMM: support[n][j] = sum_k x[n][k] * W[k][j] + lin_bias[j]
// 64x64 tile per block, 256 threads, 4x4 micro-tile. (unchanged from R1)
// ---------------------------------------------------------------------------
__global__ __launch_bounds__(256) void gemm_kernel(
    const float* __restrict__ x, const float* __restrict__ W,
    const float* __restrict__ lin_bias, float* __restrict__ support) {
  __shared__ float Wl[128 * 64];
  __shared__ float xt[128 * 64];

  const int t = threadIdx.x;
  const int bx = blockIdx.x >> 1;
  const int cy = blockIdx.x & 1;
  const int row0 = bx * 64;
  const int col0 = cy * 64;

  for (int i = t; i < 128 * 16; i += 256) {
    const int k = i >> 4, c4 = i & 15;
    float4 w4 = *(const float4*)(W + (size_t)k * D + col0 + 4 * c4);
    ((float4*)Wl)[k * 16 + c4] = w4;
  }
  for (int i = t; i < 64 * 32; i += 256) {
    const int r = i & 63, kc = i >> 6;
    float4 v = make_float4(0.f, 0.f, 0.f, 0.f);
    const int row = row0 + r;
    if (row < N_NODES) v = *(const float4*)(x + (size_t)row * D + 4 * kc);
    xt[(4 * kc + 0) * 64 + r] = v.x;
    xt[(4 * kc + 1) * 64 + r] = v.y;
    xt[(4 * kc + 2) * 64 + r] = v.z;
    xt[(4 * kc + 3) * 64 + r] = v.w;
  }
  __syncthreads();

  const int cg = t & 15;
  const int rg = t >> 4;
  const float4* Wl4 = (const float4*)Wl;
  const float4* xt4 = (const float4*)xt;

  float acc[4][4];
#pragma unroll
  for (int i = 0; i < 4; ++i)
#pragma unroll
    for (int j = 0; j < 4; ++j) acc[i][j] = 0.f;

#pragma unroll 16
  for (int k = 0; k < 128; ++k) {
    const float4 wv = Wl4[k * 16 + cg];
    const float4 xv = xt4[k * 16 + rg];
    acc[0][0] += xv.x * wv.x; acc[0][1] += xv.x * wv.y;
    acc[0][2] += xv.x * wv.z; acc[0][3] += xv.x * wv.w;
    acc[1][0] += xv.y * wv.x; acc[1][1] += xv.y * wv.y;
    acc[1][2] += xv.y * wv.z; acc[1][3] += xv.y * wv.w;
    acc[2][0] += xv.z * wv.x; acc[2][1] += xv.z * wv.y;
    acc[2][2] += xv.z * wv.z; acc[2][3] += xv.z * wv.w;
    acc[3][0] += xv.w * wv.x; acc[3][1] += xv.w * wv.y;
    acc[3][2] += xv.w * wv.z; acc[3][3] += xv.w * wv.w;
  }

  const float4 lb = *(const float4*)(lin_bias + col0 + 4 * cg);
#pragma unroll
  for (int i = 0; i < 4; ++i) {
    const int row = row0 + 4 * rg + i;
    if (row < N_NODES) {
      float4 o;
      o.x = acc[i][0] + lb.x; o.y = acc[i][1] + lb.y;
      o.z = acc[i][2] + lb.z; o.w = acc[i][3] + lb.w;
      *(float4*)(support + (size_t)row * D + col0 + 4 * cg) = o;
    }
  }
}

// ---------------------------------------------------------------------------
// CSR build: zero -> histogram -> scan -> scatter into (col,val) pairs
// ---------------------------------------------------------------------------
__global__ __launch_bounds__(256) void zero_kernel(int* __restrict__ p, int n) {
  const int i = blockIdx.x * 256 + threadIdx.x;
  if (i < n) p[i] = 0;
}

__global__ __launch_bounds__(256) void hist_kernel(
    const int* __restrict__ rows, int* __restrict__ counts) {
  const int e = blockIdx.x * 256 + threadIdx.x;   // grid sized exactly N_EDGES
  atomicAdd(&counts[rows[e] + 1], 1);
}

// Single-block inclusive scan of row_start[0..N_NODES]; also cursor[r]=start.
__global__ __launch_bounds__(1024) void scan_kernel(
    int* __restrict__ row_start, int* __restrict__ cursor) {
  __shared__ int sums[1024];
  const int N = N_NODES + 1;
  const int CHUNK = 98;                 // 1024*98 = 100352 >= 100001
  const int t = threadIdx.x;
  const int lo = t * CHUNK;
  const int hi = min(lo + CHUNK, N);

  int s = 0;
  for (int i = lo; i < hi; ++i) s += row_start[i];
  sums[t] = s;
  __syncthreads();
  for (int d = 1; d < 1024; d <<= 1) {
    int v = (t >= d) ? sums[t - d] : 0;
    __syncthreads();
    sums[t] += v;
    __syncthreads();
  }
  int run = (t == 0) ? 0 : sums[t - 1];
  for (int i = lo; i < hi; ++i) {
    run += row_start[i];
    row_start[i] = run;                 // inclusive scan == CSR offset of row i
    if (i < N_NODES) cursor[i] = run;
  }
}

__global__ __launch_bounds__(256) void build_kernel(
    const int* __restrict__ rows, const int* __restrict__ cols,
    const float* __restrict__ vals, int* __restrict__ cursor,
    int2* __restrict__ pairs) {
  const int e = blockIdx.x * 256 + threadIdx.x;   // grid sized exactly N_EDGES
  const int r = rows[e];
  const int pos = atomicAdd(&cursor[r], 1);
  pairs[pos] = make_int2(cols[e], __float_as_int(vals[e]));
}

// ---------------------------------------------------------------------------
// Gather: one 64-lane wave per row; float2/lane covers D=128. No atomics.
// out[r] = bias + sum_e val * support[col]
// ---------------------------------------------------------------------------
__global__ __launch_bounds__(256) void gather_kernel(
    const int* __restrict__ row_start, const int2* __restrict__ pairs,
    const float* __restrict__ support, const float* __restrict__ bias,
    float* __restrict__ out) {
  const int wave = blockIdx.x * 4 + (threadIdx.x >> 6);
  const int lane = threadIdx.x & 63;
  if (wave >= N_NODES) return;
  const int e0 = row_start[wave];
  const int e1 = row_start[wave + 1];

  const float2* s2 = (const float2*)support;
  float2 acc = make_float2(0.f, 0.f);
  for (int e = e0; e < e1; ++e) {
    const int2 p = pairs[e];
    const float v = __int_as_float(p.y);
    const float2 s = s2[(size_t)p.x * 64 + lane];
    acc.x += v * s.x;
    acc.y += v * s.y;
  }
  const float2 b = ((const float2*)bias)[lane];
  acc.x += b.x;
  acc.y += b.y;
  ((float2*)out)[(size_t)wave * 64 + lane] = acc;
}

// ---------------------------------------------------------------------------
// Fallback (R1 path) if workspace is too small for CSR arrays.
// ---------------------------------------------------------------------------
__global__ __launch_bounds__(256) void init_out_kernel(
    const float* __restrict__ bias, float* __restrict__ out) {
  const size_t idx = (size_t)blockIdx.x * 256 + threadIdx.x;
  const float4 b = ((const float4*)bias)[idx & 31];
  ((float4*)out)[idx] = b;
}

__global__ __launch_bounds__(256) void scatter_kernel(
    const int* __restrict__ rows, const int* __restrict__ cols,
    const float* __restrict__ vals, const float* __restrict__ support,
    float* __restrict__ out) {
  const size_t tid = (size_t)blockIdx.x * 256 + threadIdx.x;
  const int e = (int)(tid >> 5);
  const int q = (int)(tid & 31);
  const int r = rows[e];
  const int c = cols[e];
  const float v = vals[e];
  const float4 s4 = ((const float4*)support)[(size_t)c * 32 + q];
  float* o = out + (size_t)r * D + 4 * q;
  atomicAdd(o + 0, v * s4.x);
  atomicAdd(o + 1, v * s4.y);
  atomicAdd(o + 2, v * s4.z);
  atomicAdd(o + 3, v * s4.w);
}

extern "C" void kernel_launch(void* const* d_in, const int* in_sizes, int n_in,
                              void* d_out, int out_size, void* d_ws, size_t ws_size,
                              hipStream_t stream) {
  const float* x        = (const float*)d_in[0];
  const float* W        = (const float*)d_in[1];
  const float* lin_bias = (const float*)d_in[2];
  const float* bias     = (const float*)d_in[3];
  const int*   adj_rows = (const int*)d_in[4];
  const int*   adj_cols = (const int*)d_in[5];
  const float* adj_vals = (const float*)d_in[6];
  float* out = (float*)d_out;

  // Workspace layout (16B-aligned):
  //   support   : 51,200,000 B   (N_NODES*D floats)
  //   row_start : 400,016 B      (N_NODES+1 ints, padded)
  //   cursor    : 400,000 B      (N_NODES ints)
  //   pairs     : 12,800,000 B   (N_EDGES int2)
  char* wsb = (char*)d_ws;
  float* support  = (float*)wsb;
  int*   row_start = (int*)(wsb + 51200000);
  int*   cursor    = (int*)(wsb + 51200000 + 400016);
  int2*  pairs     = (int2*)(wsb + 51200000 + 400016 + 400000);
  const size_t ws_needed = 51200000ull + 400016 + 400000 + 12800000;

  // GEMM: 1563 row tiles x 2 col halves
  gemm_kernel<<<1563 * 2, 256, 0, stream>>>(x, W, lin_bias, support);

  if (ws_size >= ws_needed) {
    // CSR build + gather (no output atomics)
    zero_kernel<<<(N_NODES + 1 + 255) / 256, 256, 0, stream>>>(row_start,
                                                               N_NODES + 1);
    hist_kernel<<<N_EDGES / 256, 256, 0, stream>>>(adj_rows, row_start);
    scan_kernel<<<1, 1024, 0, stream>>>(row_start, cursor);
    build_kernel<<<N_EDGES / 256, 256, 0, stream>>>(adj_rows, adj_cols,
                                                    adj_vals, cursor, pairs);
    gather_kernel<<<N_NODES / 4, 256, 0, stream>>>(row_start, pairs, support,
                                                   bias, out);
  } else {
    // Fallback: R1 atomic scatter
    init_out_kernel<<<12500, 256, 0, stream>>>(bias, out);
    scatter_kernel<<<200000, 256, 0, stream>>>(adj_rows, adj_cols, adj_vals,
                                               support, out);
  }
}

// Round 3
// 481.586 us; speedup vs baseline: 5.9170x; 1.5138x over previous
//
#include <hip/hip_runtime.h>
#include <hip/hip_bf16.h>

#define N_NODES 100000
#define N_EDGES 1600000
#define D 128
#define SCAN_N (N_NODES + 1)   // 100001
#define SCAN_BLOCKS 98         // 98 * 1024 = 100352 >= SCAN_N

// ---------------------------------------------------------------------------
// GEMM: support[n][j] = sum_k x[n][k] * W[k][j] + lin_bias[j]
// 64x64 tile per block, 256 threads, 4x4 micro-tile.
// ---------------------------------------------------------------------------
__global__ __launch_bounds__(256) void gemm_kernel(
    const float* __restrict__ x, const float* __restrict__ W,
    const float* __restrict__ lin_bias, float* __restrict__ support) {
  __shared__ float Wl[128 * 64];
  __shared__ float xt[128 * 64];

  const int t = threadIdx.x;
  const int bx = blockIdx.x >> 1;
  const int cy = blockIdx.x & 1;
  const int row0 = bx * 64;
  const int col0 = cy * 64;

  for (int i = t; i < 128 * 16; i += 256) {
    const int k = i >> 4, c4 = i & 15;
    float4 w4 = *(const float4*)(W + (size_t)k * D + col0 + 4 * c4);
    ((float4*)Wl)[k * 16 + c4] = w4;
  }
  for (int i = t; i < 64 * 32; i += 256) {
    const int r = i & 63, kc = i >> 6;
    float4 v = make_float4(0.f, 0.f, 0.f, 0.f);
    const int row = row0 + r;
    if (row < N_NODES) v = *(const float4*)(x + (size_t)row * D + 4 * kc);
    xt[(4 * kc + 0) * 64 + r] = v.x;
    xt[(4 * kc + 1) * 64 + r] = v.y;
    xt[(4 * kc + 2) * 64 + r] = v.z;
    xt[(4 * kc + 3) * 64 + r] = v.w;
  }
  __syncthreads();

  const int cg = t & 15;
  const int rg = t >> 4;
  const float4* Wl4 = (const float4*)Wl;
  const float4* xt4 = (const float4*)xt;

  float acc[4][4];
#pragma unroll
  for (int i = 0; i < 4; ++i)
#pragma unroll
    for (int j = 0; j < 4; ++j) acc[i][j] = 0.f;

#pragma unroll 16
  for (int k = 0; k < 128; ++k) {
    const float4 wv = Wl4[k * 16 + cg];
    const float4 xv = xt4[k * 16 + rg];
    acc[0][0] += xv.x * wv.x; acc[0][1] += xv.x * wv.y;
    acc[0][2] += xv.x * wv.z; acc[0][3] += xv.x * wv.w;
    acc[1][0] += xv.y * wv.x; acc[1][1] += xv.y * wv.y;
    acc[1][2] += xv.y * wv.z; acc[1][3] += xv.y * wv.w;
    acc[2][0] += xv.z * wv.x; acc[2][1] += xv.z * wv.y;
    acc[2][2] += xv.z * wv.z; acc[2][3] += xv.z * wv.w;
    acc[3][0] += xv.w * wv.x; acc[3][1] += xv.w * wv.y;
    acc[3][2] += xv.w * wv.z; acc[3][3] += xv.w * wv.w;
  }

  const float4 lb = *(const float4*)(lin_bias + col0 + 4 * cg);
#pragma unroll
  for (int i = 0; i < 4; ++i) {
    const int row = row0 + 4 * rg + i;
    if (row < N_NODES) {
      float4 o;
      o.x = acc[i][0] + lb.x; o.y = acc[i][1] + lb.y;
      o.z = acc[i][2] + lb.z; o.w = acc[i][3] + lb.w;
      *(float4*)(support + (size_t)row * D + col0 + 4 * cg) = o;
    }
  }
}

// ---------------------------------------------------------------------------
// CSR build: zero -> histogram -> 3-phase multi-block scan -> edge scatter
// ---------------------------------------------------------------------------
__global__ __launch_bounds__(256) void zero_kernel(int* __restrict__ p, int n) {
  const int i = blockIdx.x * 256 + threadIdx.x;
  if (i < n) p[i] = 0;
}

__global__ __launch_bounds__(256) void hist_kernel(
    const int* __restrict__ rows, int* __restrict__ counts) {
  const int e = blockIdx.x * 256 + threadIdx.x;   // grid == N_EDGES exactly
  atomicAdd(&counts[rows[e] + 1], 1);
}

// Phase 1: per-block inclusive scan (1024 elems/block), in place; block sums.
__global__ __launch_bounds__(1024) void scan1_kernel(
    int* __restrict__ row_start, int* __restrict__ partials) {
  __shared__ int s[1024];
  const int t = threadIdx.x;
  const int i = blockIdx.x * 1024 + t;
  s[t] = (i < SCAN_N) ? row_start[i] : 0;
  __syncthreads();
#pragma unroll
  for (int d = 1; d < 1024; d <<= 1) {
    const int v = (t >= d) ? s[t - d] : 0;
    __syncthreads();
    s[t] += v;
    __syncthreads();
  }
  if (i < SCAN_N) row_start[i] = s[t];
  if (t == 1023) partials[blockIdx.x] = s[1023];
}

// Phase 2: single small block turns partials into exclusive block offsets.
__global__ __launch_bounds__(128) void scan2_kernel(int* __restrict__ partials) {
  __shared__ int s[128];
  const int t = threadIdx.x;
  s[t] = (t < SCAN_BLOCKS) ? partials[t] : 0;
  __syncthreads();
#pragma unroll
  for (int d = 1; d < 128; d <<= 1) {
    const int v = (t >= d) ? s[t - d] : 0;
    __syncthreads();
    s[t] += v;
    __syncthreads();
  }
  if (t < SCAN_BLOCKS) partials[t] = (t == 0) ? 0 : s[t - 1];
}

// Phase 3: add block offset; also init per-row cursor.
__global__ __launch_bounds__(1024) void scan3_kernel(
    int* __restrict__ row_start, const int* __restrict__ partials,
    int* __restrict__ cursor) {
  const int i = blockIdx.x * 1024 + threadIdx.x;
  if (i < SCAN_N) {
    const int v = row_start[i] + partials[blockIdx.x];
    row_start[i] = v;
    if (i < N_NODES) cursor[i] = v;
  }
}

__global__ __launch_bounds__(256) void build_kernel(
    const int* __restrict__ rows, const int* __restrict__ cols,
    const float* __restrict__ vals, int* __restrict__ cursor,
    int2* __restrict__ pairs) {
  const int e = blockIdx.x * 256 + threadIdx.x;   // grid == N_EDGES exactly
  const int r = rows[e];
  const int pos = atomicAdd(&cursor[r], 1);
  pairs[pos] = make_int2(cols[e], __float_as_int(vals[e]));
}

// ---------------------------------------------------------------------------
// Gather: one 64-lane wave per row; float2/lane covers D=128. No atomics.
// Edge loop unrolled x2 for two independent load chains.
// ---------------------------------------------------------------------------
__global__ __launch_bounds__(256) void gather_kernel(
    const int* __restrict__ row_start, const int2* __restrict__ pairs,
    const float* __restrict__ support, const float* __restrict__ bias,
    float* __restrict__ out) {
  const int wave = blockIdx.x * 4 + (threadIdx.x >> 6);
  const int lane = threadIdx.x & 63;
  if (wave >= N_NODES) return;
  const int e0 = row_start[wave];
  const int e1 = row_start[wave + 1];

  const float2* s2 = (const float2*)support;
  float2 acc0 = make_float2(0.f, 0.f);
  float2 acc1 = make_float2(0.f, 0.f);
  int e = e0;
  for (; e + 1 < e1; e += 2) {
    const int2 pa = pairs[e];
    const int2 pb = pairs[e + 1];
    const float2 sa = s2[(size_t)pa.x * 64 + lane];
    const float2 sb = s2[(size_t)pb.x * 64 + lane];
    const float va = __int_as_float(pa.y);
    const float vb = __int_as_float(pb.y);
    acc0.x += va * sa.x; acc0.y += va * sa.y;
    acc1.x += vb * sb.x; acc1.y += vb * sb.y;
  }
  if (e < e1) {
    const int2 pa = pairs[e];
    const float va = __int_as_float(pa.y);
    const float2 sa = s2[(size_t)pa.x * 64 + lane];
    acc0.x += va * sa.x; acc0.y += va * sa.y;
  }
  const float2 b = ((const float2*)bias)[lane];
  float2 r;
  r.x = acc0.x + acc1.x + b.x;
  r.y = acc0.y + acc1.y + b.y;
  ((float2*)out)[(size_t)wave * 64 + lane] = r;
}

// ---------------------------------------------------------------------------
// Fallback (atomic path) if workspace is too small for CSR arrays.
// ---------------------------------------------------------------------------
__global__ __launch_bounds__(256) void init_out_kernel(
    const float* __restrict__ bias, float* __restrict__ out) {
  const size_t idx = (size_t)blockIdx.x * 256 + threadIdx.x;
  const float4 b = ((const float4*)bias)[idx & 31];
  ((float4*)out)[idx] = b;
}

__global__ __launch_bounds__(256) void scatter_kernel(
    const int* __restrict__ rows, const int* __restrict__ cols,
    const float* __restrict__ vals, const float* __restrict__ support,
    float* __restrict__ out) {
  const size_t tid = (size_t)blockIdx.x * 256 + threadIdx.x;
  const int e = (int)(tid >> 5);
  const int q = (int)(tid & 31);
  const int r = rows[e];
  const int c = cols[e];
  const float v = vals[e];
  const float4 s4 = ((const float4*)support)[(size_t)c * 32 + q];
  float* o = out + (size_t)r * D + 4 * q;
  atomicAdd(o + 0, v * s4.x);
  atomicAdd(o + 1, v * s4.y);
  atomicAdd(o + 2, v * s4.z);
  atomicAdd(o + 3, v * s4.w);
}

extern "C" void kernel_launch(void* const* d_in, const int* in_sizes, int n_in,
                              void* d_out, int out_size, void* d_ws, size_t ws_size,
                              hipStream_t stream) {
  const float* x        = (const float*)d_in[0];
  const float* W        = (const float*)d_in[1];
  const float* lin_bias = (const float*)d_in[2];
  const float* bias     = (const float*)d_in[3];
  const int*   adj_rows = (const int*)d_in[4];
  const int*   adj_cols = (const int*)d_in[5];
  const float* adj_vals = (const float*)d_in[6];
  float* out = (float*)d_out;

  // Workspace layout (16B-aligned):
  //   support   : 51,200,000 B  (N_NODES*D floats)
  //   row_start : 400,016 B     (SCAN_N ints, padded)
  //   cursor    : 400,000 B     (N_NODES ints)
  //   pairs     : 12,800,000 B  (N_EDGES int2)
  //   partials  : 1,024 B       (SCAN_BLOCKS ints, padded)
  char* wsb = (char*)d_ws;
  float* support   = (float*)wsb;
  int*   row_start = (int*)(wsb + 51200000);
  int*   cursor    = (int*)(wsb + 51200000 + 400016);
  int2*  pairs     = (int2*)(wsb + 51200000 + 400016 + 400000);
  int*   partials  = (int*)(wsb + 51200000 + 400016 + 400000 + 12800000);
  const size_t ws_needed = 51200000ull + 400016 + 400000 + 12800000 + 1024;

  gemm_kernel<<<1563 * 2, 256, 0, stream>>>(x, W, lin_bias, support);

  if (ws_size >= ws_needed) {
    zero_kernel<<<(SCAN_N + 255) / 256, 256, 0, stream>>>(row_start, SCAN_N);
    hist_kernel<<<N_EDGES / 256, 256, 0, stream>>>(adj_rows, row_start);
    scan1_kernel<<<SCAN_BLOCKS, 1024, 0, stream>>>(row_start, partials);
    scan2_kernel<<<1, 128, 0, stream>>>(partials);
    scan3_kernel<<<SCAN_BLOCKS, 1024, 0, stream>>>(row_start, partials, cursor);
    build_kernel<<<N_EDGES / 256, 256, 0, stream>>>(adj_rows, adj_cols,
                                                    adj_vals, cursor, pairs);
    gather_kernel<<<N_NODES / 4, 256, 0, stream>>>(row_start, pairs, support,
                                                   bias, out);
  } else {
    init_out_kernel<<<12500, 256, 0, stream>>>(bias, out);
    scatter_kernel<<<200000, 256, 0, stream>>>(adj_rows, adj_cols, adj_vals,
                                               support, out);
  }
}

// Round 4
// 399.162 us; speedup vs baseline: 7.1389x; 1.2065x over previous
//
#include <hip/hip_runtime.h>
#include <hip/hip_bf16.h>

#define N_NODES 100000
#define N_EDGES 1600000
#define D 128
#define SCAN_N (N_NODES + 1)   // 100001
#define SCAN_BLOCKS 98         // 98 * 1024 = 100352 >= SCAN_N
#define NGROUP 8               // hist privatization groups

typedef __attribute__((ext_vector_type(8))) short short8;
typedef __attribute__((ext_vector_type(4))) float f32x4;

__device__ inline unsigned short f2bf(float f) {
  union { float f; unsigned u; } c; c.f = f;
  const unsigned u = c.u;
  return (unsigned short)((u + 0x7FFF + ((u >> 16) & 1)) >> 16);  // RNE
}

// ---------------------------------------------------------------------------
// GEMM (bf16 MFMA): support[n][j] = sum_k x[n][k]*W[k][j] + lin_bias[j]
// 128 rows/block, 256 threads (4 waves), each wave 32 rows x 128 cols.
// LDS: Wt[n][k] and xb[r][k] in bf16, k padded 128->136 (2-way conflicts only).
// ---------------------------------------------------------------------------
#define GR 128
#define LDK 136
__global__ __launch_bounds__(256) void gemm_kernel(
    const float* __restrict__ x, const float* __restrict__ W,
    const float* __restrict__ lin_bias, float* __restrict__ support) {
  __shared__ unsigned short Wt[128 * LDK];  // W transposed: Wt[n][k]
  __shared__ unsigned short xb[GR * LDK];   // xb[r][k]
  const int t = threadIdx.x;
  const int row0 = blockIdx.x * GR;

  // Stage W transposed (coalesced read, scattered LDS write; once per block).
  for (int i = t; i < 128 * 32; i += 256) {
    const int k = i >> 5, n4 = (i & 31) * 4;
    const float4 w = *(const float4*)(W + k * D + n4);
    Wt[(n4 + 0) * LDK + k] = f2bf(w.x);
    Wt[(n4 + 1) * LDK + k] = f2bf(w.y);
    Wt[(n4 + 2) * LDK + k] = f2bf(w.z);
    Wt[(n4 + 3) * LDK + k] = f2bf(w.w);
  }
  // Stage x rows (coalesced read, contiguous LDS write).
  for (int i = t; i < GR * 32; i += 256) {
    const int r = i >> 5, k4 = (i & 31) * 4;
    const int row = row0 + r;
    float4 v = make_float4(0.f, 0.f, 0.f, 0.f);
    if (row < N_NODES) v = *(const float4*)(x + (size_t)row * D + k4);
    unsigned short* p = &xb[r * LDK + k4];
    p[0] = f2bf(v.x); p[1] = f2bf(v.y); p[2] = f2bf(v.z); p[3] = f2bf(v.w);
  }
  __syncthreads();

  const int w = t >> 6;        // wave 0..3: rows w*32 .. w*32+31
  const int lane = t & 63;
  const int m16 = lane & 15;
  const int quad = lane >> 4;

  f32x4 acc[2][8];
#pragma unroll
  for (int rt = 0; rt < 2; ++rt)
#pragma unroll
    for (int ct = 0; ct < 8; ++ct) acc[rt][ct] = (f32x4){0.f, 0.f, 0.f, 0.f};

#pragma unroll
  for (int kc = 0; kc < 4; ++kc) {
    const int kof = kc * 32 + quad * 8;   // 16B-aligned within padded row
    short8 a0 = *(const short8*)&xb[(w * 32 + 0 * 16 + m16) * LDK + kof];
    short8 a1 = *(const short8*)&xb[(w * 32 + 1 * 16 + m16) * LDK + kof];
#pragma unroll
    for (int ct = 0; ct < 8; ++ct) {
      const short8 b = *(const short8*)&Wt[(ct * 16 + m16) * LDK + kof];
      acc[0][ct] = __builtin_amdgcn_mfma_f32_16x16x32_bf16(a0, b, acc[0][ct], 0, 0, 0);
      acc[1][ct] = __builtin_amdgcn_mfma_f32_16x16x32_bf16(a1, b, acc[1][ct], 0, 0, 0);
    }
  }

  // Epilogue: C/D layout col=lane&15, row=quad*4+reg (m89-verified).
#pragma unroll
  for (int ct = 0; ct < 8; ++ct) {
    const int col = ct * 16 + m16;
    const float lb = lin_bias[col];
#pragma unroll
    for (int rt = 0; rt < 2; ++rt) {
      const int rbase = row0 + w * 32 + rt * 16 + quad * 4;
#pragma unroll
      for (int i = 0; i < 4; ++i) {
        const int row = rbase + i;
        if (row < N_NODES)
          support[(size_t)row * D + col] = acc[rt][ct][i] + lb;
      }
    }
  }
}

// ---------------------------------------------------------------------------
// CSR build, atomic-light:
//   zero -> hist(rank) -> sumrows -> scan(x3) -> scanB(gofs) -> build(no atomic)
// ---------------------------------------------------------------------------
__global__ __launch_bounds__(256) void zero_kernel(int* __restrict__ p, int n) {
  const int i = blockIdx.x * 256 + threadIdx.x;
  if (i < n) p[i] = 0;
}

// count[r*8+g]; rank[e] = this edge's arrival index within (g, r).
__global__ __launch_bounds__(256) void hist_kernel(
    const int* __restrict__ rows, int* __restrict__ count,
    unsigned char* __restrict__ rank) {
  const int e = blockIdx.x * 256 + threadIdx.x;   // grid == N_EDGES exactly
  const int g = blockIdx.x & (NGROUP - 1);
  const int r = rows[e];
  const int rg = atomicAdd(&count[r * NGROUP + g], 1);
  rank[e] = (unsigned char)rg;
}

// row_start[r+1] = total degree of row r; row_start[0] = 0.
__global__ __launch_bounds__(256) void sumrows_kernel(
    const int* __restrict__ count, int* __restrict__ row_start) {
  const int r = blockIdx.x * 256 + threadIdx.x;
  if (r < N_NODES) {
    const int4* c4 = (const int4*)(count + r * NGROUP);
    const int4 a = c4[0], b = c4[1];
    row_start[r + 1] = a.x + a.y + a.z + a.w + b.x + b.y + b.z + b.w;
    if (r == 0) row_start[0] = 0;
  }
}

__global__ __launch_bounds__(1024) void scan1_kernel(
    int* __restrict__ row_start, int* __restrict__ partials) {
  __shared__ int s[1024];
  const int t = threadIdx.x;
  const int i = blockIdx.x * 1024 + t;
  s[t] = (i < SCAN_N) ? row_start[i] : 0;
  __syncthreads();
#pragma unroll
  for (int d = 1; d < 1024; d <<= 1) {
    const int v = (t >= d) ? s[t - d] : 0;
    __syncthreads();
    s[t] += v;
    __syncthreads();
  }
  if (i < SCAN_N) row_start[i] = s[t];
  if (t == 1023) partials[blockIdx.x] = s[1023];
}

__global__ __launch_bounds__(128) void scan2_kernel(int* __restrict__ partials) {
  __shared__ int s[128];
  const int t = threadIdx.x;
  s[t] = (t < SCAN_BLOCKS) ? partials[t] : 0;
  __syncthreads();
#pragma unroll
  for (int d = 1; d < 128; d <<= 1) {
    const int v = (t >= d) ? s[t - d] : 0;
    __syncthreads();
    s[t] += v;
    __syncthreads();
  }
  if (t < SCAN_BLOCKS) partials[t] = (t == 0) ? 0 : s[t - 1];
}

__global__ __launch_bounds__(1024) void scan3_kernel(
    int* __restrict__ row_start, const int* __restrict__ partials) {
  const int i = blockIdx.x * 1024 + threadIdx.x;
  if (i < SCAN_N) row_start[i] += partials[blockIdx.x];
}

// In place: count[r*8+g] becomes gofs = row_start[r] + sum_{g'<g} count[r*8+g'].
__global__ __launch_bounds__(256) void scanb_kernel(
    const int* __restrict__ row_start, int* __restrict__ count) {
  const int r = blockIdx.x * 256 + threadIdx.x;
  if (r < N_NODES) {
    int* c = count + r * NGROUP;
    int base = row_start[r];
#pragma unroll
    for (int g = 0; g < NGROUP; ++g) {
      const int v = c[g];
      c[g] = base;
      base += v;
    }
  }
}

// No atomics: pos = gofs[g][r] + rank[e]. Packed pair: (col<<15) | q15(val).
__global__ __launch_bounds__(256) void build_kernel(
    const int* __restrict__ rows, const int* __restrict__ cols,
    const float* __restrict__ vals, const int* __restrict__ gofs,
    const unsigned char* __restrict__ rank, unsigned* __restrict__ pairs) {
  const int e = blockIdx.x * 256 + threadIdx.x;   // grid == N_EDGES exactly
  const int g = blockIdx.x & (NGROUP - 1);
  const int r = rows[e];
  const int pos = gofs[r * NGROUP + g] + (int)rank[e];
  const unsigned q = (unsigned)(vals[e] * 32767.f + 0.5f);
  pairs[pos] = ((unsigned)cols[e] << 15) | q;
}

// ---------------------------------------------------------------------------
// Gather: one 64-lane wave per row; float2/lane; x2 unroll; no atomics.
// ---------------------------------------------------------------------------
__global__ __launch_bounds__(256) void gather_kernel(
    const int* __restrict__ row_start, const unsigned* __restrict__ pairs,
    const float* __restrict__ support, const float* __restrict__ bias,
    float* __restrict__ out) {
  const int wave = blockIdx.x * 4 + (threadIdx.x >> 6);
  const int lane = threadIdx.x & 63;
  if (wave >= N_NODES) return;
  const int e0 = row_start[wave];
  const int e1 = row_start[wave + 1];

  const float2* s2 = (const float2*)support;
  float2 acc0 = make_float2(0.f, 0.f);
  float2 acc1 = make_float2(0.f, 0.f);
  int e = e0;
  for (; e + 1 < e1; e += 2) {
    const unsigned pa = pairs[e];
    const unsigned pb = pairs[e + 1];
    const float2 sa = s2[(size_t)(pa >> 15) * 64 + lane];
    const float2 sb = s2[(size_t)(pb >> 15) * 64 + lane];
    const float va = (float)(pa & 0x7FFFu) * (1.f / 32767.f);
    const float vb = (float)(pb & 0x7FFFu) * (1.f / 32767.f);
    acc0.x += va * sa.x; acc0.y += va * sa.y;
    acc1.x += vb * sb.x; acc1.y += vb * sb.y;
  }
  if (e < e1) {
    const unsigned pa = pairs[e];
    const float va = (float)(pa & 0x7FFFu) * (1.f / 32767.f);
    const float2 sa = s2[(size_t)(pa >> 15) * 64 + lane];
    acc0.x += va * sa.x; acc0.y += va * sa.y;
  }
  const float2 b = ((const float2*)bias)[lane];
  float2 r;
  r.x = acc0.x + acc1.x + b.x;
  r.y = acc0.y + acc1.y + b.y;
  ((float2*)out)[(size_t)wave * 64 + lane] = r;
}

// ---------------------------------------------------------------------------
// Fallback (atomic path) if workspace is too small.
// ---------------------------------------------------------------------------
__global__ __launch_bounds__(256) void init_out_kernel(
    const float* __restrict__ bias, float* __restrict__ out) {
  const size_t idx = (size_t)blockIdx.x * 256 + threadIdx.x;
  const float4 b = ((const float4*)bias)[idx & 31];
  ((float4*)out)[idx] = b;
}

__global__ __launch_bounds__(256) void scatter_kernel(
    const int* __restrict__ rows, const int* __restrict__ cols,
    const float* __restrict__ vals, const float* __restrict__ support,
    float* __restrict__ out) {
  const size_t tid = (size_t)blockIdx.x * 256 + threadIdx.x;
  const int e = (int)(tid >> 5);
  const int q = (int)(tid & 31);
  const int r = rows[e];
  const int c = cols[e];
  const float v = vals[e];
  const float4 s4 = ((const float4*)support)[(size_t)c * 32 + q];
  float* o = out + (size_t)r * D + 4 * q;
  atomicAdd(o + 0, v * s4.x);
  atomicAdd(o + 1, v * s4.y);
  atomicAdd(o + 2, v * s4.z);
  atomicAdd(o + 3, v * s4.w);
}

extern "C" void kernel_launch(void* const* d_in, const int* in_sizes, int n_in,
                              void* d_out, int out_size, void* d_ws, size_t ws_size,
                              hipStream_t stream) {
  const float* x        = (const float*)d_in[0];
  const float* W        = (const float*)d_in[1];
  const float* lin_bias = (const float*)d_in[2];
  const float* bias     = (const float*)d_in[3];
  const int*   adj_rows = (const int*)d_in[4];
  const int*   adj_cols = (const int*)d_in[5];
  const float* adj_vals = (const float*)d_in[6];
  float* out = (float*)d_out;

  // Workspace layout (16B-aligned offsets):
  //   support   : 51,200,000 B  (N_NODES*D f32)
  //   row_start :    400,016 B  (SCAN_N ints, padded)
  //   count/gofs:  3,200,000 B  (N_NODES*8 ints)
  //   rank      :  1,600,000 B  (N_EDGES u8)
  //   pairs     :  6,400,000 B  (N_EDGES u32, packed col|q15)
  //   partials  :        512 B
  char* wsb = (char*)d_ws;
  float*         support   = (float*)wsb;
  int*           row_start = (int*)(wsb + 51200000);
  int*           count     = (int*)(wsb + 51600016);
  unsigned char* rank      = (unsigned char*)(wsb + 54800016);
  unsigned*      pairs     = (unsigned*)(wsb + 56400016);
  int*           partials  = (int*)(wsb + 62800016);
  const size_t ws_needed = 62800528;

  gemm_kernel<<<(N_NODES + GR - 1) / GR, 256, 0, stream>>>(x, W, lin_bias,
                                                           support);

  if (ws_size >= ws_needed) {
    zero_kernel<<<(N_NODES * NGROUP) / 256, 256, 0, stream>>>(count,
                                                              N_NODES * NGROUP);
    hist_kernel<<<N_EDGES / 256, 256, 0, stream>>>(adj_rows, count, rank);
    sumrows_kernel<<<(N_NODES + 255) / 256, 256, 0, stream>>>(count, row_start);
    scan1_kernel<<<SCAN_BLOCKS, 1024, 0, stream>>>(row_start, partials);
    scan2_kernel<<<1, 128, 0, stream>>>(partials);
    scan3_kernel<<<SCAN_BLOCKS, 1024, 0, stream>>>(row_start, partials);
    scanb_kernel<<<(N_NODES + 255) / 256, 256, 0, stream>>>(row_start, count);
    build_kernel<<<N_EDGES / 256, 256, 0, stream>>>(adj_rows, adj_cols,
                                                    adj_vals, count, rank,
                                                    pairs);
    gather_kernel<<<N_NODES / 4, 256, 0, stream>>>(row_start, pairs, support,
                                                   bias, out);
  } else {
    init_out_kernel<<<12500, 256, 0, stream>>>(bias, out);
    scatter_kernel<<<200000, 256, 0, stream>>>(adj_rows, adj_cols, adj_vals,
                                               support, out);
  }
}

// Round 5
// 370.036 us; speedup vs baseline: 7.7008x; 1.0787x over previous
//
#include <hip/hip_runtime.h>
#include <hip/hip_bf16.h>

#define N_NODES 100000
#define N_EDGES 1600000
#define D 128
#define SCAN_N (N_NODES + 1)   // 100001
#define SCAN_BLOCKS 98         // 98 * 1024 = 100352 >= SCAN_N
#define NGROUP 8               // hist privatization groups

typedef __attribute__((ext_vector_type(8))) short short8;
typedef __attribute__((ext_vector_type(4))) float f32x4;

__device__ inline unsigned short f2bf(float f) {
  union { float f; unsigned u; } c; c.f = f;
  const unsigned u = c.u;
  return (unsigned short)((u + 0x7FFF + ((u >> 16) & 1)) >> 16);  // RNE
}
__device__ inline float bflo(unsigned u) { return __int_as_float(u << 16); }
__device__ inline float bfhi(unsigned u) { return __int_as_float(u & 0xFFFF0000u); }

// ---------------------------------------------------------------------------
// GEMM (bf16 MFMA): support[n][j] = sum_k x[n][k]*W[k][j] + lin_bias[j]
// 128 rows/block, 256 threads (4 waves), each wave 32 rows x 128 cols.
// Output support stored as bf16 (gather reads it as packed dwords).
// ---------------------------------------------------------------------------
#define GR 128
#define LDK 136
__global__ __launch_bounds__(256) void gemm_kernel(
    const float* __restrict__ x, const float* __restrict__ W,
    const float* __restrict__ lin_bias, unsigned short* __restrict__ support) {
  __shared__ unsigned short Wt[128 * LDK];  // W transposed: Wt[n][k]
  __shared__ unsigned short xb[GR * LDK];   // xb[r][k]
  const int t = threadIdx.x;
  const int row0 = blockIdx.x * GR;

  for (int i = t; i < 128 * 32; i += 256) {
    const int k = i >> 5, n4 = (i & 31) * 4;
    const float4 w = *(const float4*)(W + k * D + n4);
    Wt[(n4 + 0) * LDK + k] = f2bf(w.x);
    Wt[(n4 + 1) * LDK + k] = f2bf(w.y);
    Wt[(n4 + 2) * LDK + k] = f2bf(w.z);
    Wt[(n4 + 3) * LDK + k] = f2bf(w.w);
  }
  for (int i = t; i < GR * 32; i += 256) {
    const int r = i >> 5, k4 = (i & 31) * 4;
    const int row = row0 + r;
    float4 v = make_float4(0.f, 0.f, 0.f, 0.f);
    if (row < N_NODES) v = *(const float4*)(x + (size_t)row * D + k4);
    unsigned short* p = &xb[r * LDK + k4];
    p[0] = f2bf(v.x); p[1] = f2bf(v.y); p[2] = f2bf(v.z); p[3] = f2bf(v.w);
  }
  __syncthreads();

  const int w = t >> 6;
  const int lane = t & 63;
  const int m16 = lane & 15;
  const int quad = lane >> 4;

  f32x4 acc[2][8];
#pragma unroll
  for (int rt = 0; rt < 2; ++rt)
#pragma unroll
    for (int ct = 0; ct < 8; ++ct) acc[rt][ct] = (f32x4){0.f, 0.f, 0.f, 0.f};

#pragma unroll
  for (int kc = 0; kc < 4; ++kc) {
    const int kof = kc * 32 + quad * 8;
    short8 a0 = *(const short8*)&xb[(w * 32 + 0 * 16 + m16) * LDK + kof];
    short8 a1 = *(const short8*)&xb[(w * 32 + 1 * 16 + m16) * LDK + kof];
#pragma unroll
    for (int ct = 0; ct < 8; ++ct) {
      const short8 b = *(const short8*)&Wt[(ct * 16 + m16) * LDK + kof];
      acc[0][ct] = __builtin_amdgcn_mfma_f32_16x16x32_bf16(a0, b, acc[0][ct], 0, 0, 0);
      acc[1][ct] = __builtin_amdgcn_mfma_f32_16x16x32_bf16(a1, b, acc[1][ct], 0, 0, 0);
    }
  }

  // Epilogue: C/D layout col=lane&15, row=quad*4+reg. bf16 stores.
#pragma unroll
  for (int ct = 0; ct < 8; ++ct) {
    const int col = ct * 16 + m16;
    const float lb = lin_bias[col];
#pragma unroll
    for (int rt = 0; rt < 2; ++rt) {
      const int rbase = row0 + w * 32 + rt * 16 + quad * 4;
#pragma unroll
      for (int i = 0; i < 4; ++i) {
        const int row = rbase + i;
        if (row < N_NODES)
          support[(size_t)row * D + col] = f2bf(acc[rt][ct][i] + lb);
      }
    }
  }
}

// ---------------------------------------------------------------------------
// CSR build: zero -> hist(rank) -> scan1(deg from count) -> scan2 ->
//            scan3(row_start + gofs) -> build(no atomics)
// ---------------------------------------------------------------------------
__global__ __launch_bounds__(256) void zero_kernel(int* __restrict__ p, int n) {
  const int i = blockIdx.x * 256 + threadIdx.x;
  if (i < n) p[i] = 0;
}

__global__ __launch_bounds__(256) void hist_kernel(
    const int* __restrict__ rows, int* __restrict__ count,
    unsigned char* __restrict__ rank) {
  const int e = blockIdx.x * 256 + threadIdx.x;   // grid == N_EDGES exactly
  const int g = blockIdx.x & (NGROUP - 1);
  const int r = rows[e];
  const int rg = atomicAdd(&count[r * NGROUP + g], 1);
  rank[e] = (unsigned char)rg;
}

// Per-block inclusive scan of degrees (deg[i] = degree of node i-1, deg[0]=0).
__global__ __launch_bounds__(1024) void scan1_kernel(
    const int* __restrict__ count, int* __restrict__ row_start,
    int* __restrict__ partials) {
  __shared__ int s[1024];
  const int t = threadIdx.x;
  const int i = blockIdx.x * 1024 + t;
  int deg = 0;
  if (i >= 1 && i <= N_NODES) {
    const int4* c4 = (const int4*)(count + (size_t)(i - 1) * NGROUP);
    const int4 a = c4[0], b = c4[1];
    deg = a.x + a.y + a.z + a.w + b.x + b.y + b.z + b.w;
  }
  s[t] = deg;
  __syncthreads();
#pragma unroll
  for (int d = 1; d < 1024; d <<= 1) {
    const int v = (t >= d) ? s[t - d] : 0;
    __syncthreads();
    s[t] += v;
    __syncthreads();
  }
  if (i < SCAN_N) row_start[i] = s[t];
  if (t == 1023) partials[blockIdx.x] = s[1023];
}

__global__ __launch_bounds__(128) void scan2_kernel(int* __restrict__ partials) {
  __shared__ int s[128];
  const int t = threadIdx.x;
  s[t] = (t < SCAN_BLOCKS) ? partials[t] : 0;
  __syncthreads();
#pragma unroll
  for (int d = 1; d < 128; d <<= 1) {
    const int v = (t >= d) ? s[t - d] : 0;
    __syncthreads();
    s[t] += v;
    __syncthreads();
  }
  if (t < SCAN_BLOCKS) partials[t] = (t == 0) ? 0 : s[t - 1];
}

// Finalize row_start; convert count[r*8+g] in place into group offsets.
__global__ __launch_bounds__(1024) void scan3_kernel(
    int* __restrict__ row_start, const int* __restrict__ partials,
    int* __restrict__ count) {
  const int i = blockIdx.x * 1024 + threadIdx.x;
  if (i < SCAN_N) {
    const int v = row_start[i] + partials[blockIdx.x];
    row_start[i] = v;
    if (i < N_NODES) {
      int* c = count + (size_t)i * NGROUP;
      int base = v;
#pragma unroll
      for (int g = 0; g < NGROUP; ++g) {
        const int tmp = c[g];
        c[g] = base;
        base += tmp;
      }
    }
  }
}

// No atomics: pos = gofs[r][g] + rank[e]. Packed pair: (col<<15) | q15(val).
__global__ __launch_bounds__(256) void build_kernel(
    const int* __restrict__ rows, const int* __restrict__ cols,
    const float* __restrict__ vals, const int* __restrict__ gofs,
    const unsigned char* __restrict__ rank, unsigned* __restrict__ pairs) {
  const int e = blockIdx.x * 256 + threadIdx.x;   // grid == N_EDGES exactly
  const int g = blockIdx.x & (NGROUP - 1);
  const int r = rows[e];
  const int pos = gofs[(size_t)r * NGROUP + g] + (int)rank[e];
  const unsigned q = (unsigned)(vals[e] * 32767.f + 0.5f);
  pairs[pos] = ((unsigned)cols[e] << 15) | q;
}

// ---------------------------------------------------------------------------
// Gather: one 64-lane wave per row; lane handles cols 2*lane, 2*lane+1.
// support is bf16 packed: dword lane of row = cols {2*lane, 2*lane+1}.
// ---------------------------------------------------------------------------
__global__ __launch_bounds__(256) void gather_kernel(
    const int* __restrict__ row_start, const unsigned* __restrict__ pairs,
    const unsigned* __restrict__ support, const float* __restrict__ bias,
    float* __restrict__ out) {
  const int wave = blockIdx.x * 4 + (threadIdx.x >> 6);
  const int lane = threadIdx.x & 63;
  if (wave >= N_NODES) return;
  const int e0 = row_start[wave];
  const int e1 = row_start[wave + 1];

  float2 acc0 = make_float2(0.f, 0.f);
  float2 acc1 = make_float2(0.f, 0.f);
  int e = e0;
  for (; e + 1 < e1; e += 2) {
    const unsigned pa = pairs[e];
    const unsigned pb = pairs[e + 1];
    const unsigned sa = support[(size_t)(pa >> 15) * 64 + lane];
    const unsigned sb = support[(size_t)(pb >> 15) * 64 + lane];
    const float va = (float)(pa & 0x7FFFu) * (1.f / 32767.f);
    const float vb = (float)(pb & 0x7FFFu) * (1.f / 32767.f);
    acc0.x += va * bflo(sa); acc0.y += va * bfhi(sa);
    acc1.x += vb * bflo(sb); acc1.y += vb * bfhi(sb);
  }
  if (e < e1) {
    const unsigned pa = pairs[e];
    const unsigned sa = support[(size_t)(pa >> 15) * 64 + lane];
    const float va = (float)(pa & 0x7FFFu) * (1.f / 32767.f);
    acc0.x += va * bflo(sa); acc0.y += va * bfhi(sa);
  }
  const float2 b = ((const float2*)bias)[lane];
  float2 r;
  r.x = acc0.x + acc1.x + b.x;
  r.y = acc0.y + acc1.y + b.y;
  ((float2*)out)[(size_t)wave * 64 + lane] = r;
}

// ---------------------------------------------------------------------------
// Fallback (atomic path, bf16 support) if workspace is too small.
// ---------------------------------------------------------------------------
__global__ __launch_bounds__(256) void init_out_kernel(
    const float* __restrict__ bias, float* __restrict__ out) {
  const size_t idx = (size_t)blockIdx.x * 256 + threadIdx.x;
  const float4 b = ((const float4*)bias)[idx & 31];
  ((float4*)out)[idx] = b;
}

__global__ __launch_bounds__(256) void scatter_kernel(
    const int* __restrict__ rows, const int* __restrict__ cols,
    const float* __restrict__ vals, const unsigned* __restrict__ support,
    float* __restrict__ out) {
  const size_t tid = (size_t)blockIdx.x * 256 + threadIdx.x;
  const int e = (int)(tid >> 5);
  const int q = (int)(tid & 31);
  const int r = rows[e];
  const int c = cols[e];
  const float v = vals[e];
  const uint2 s = ((const uint2*)support)[(size_t)c * 32 + q];
  float* o = out + (size_t)r * D + 4 * q;
  atomicAdd(o + 0, v * bflo(s.x));
  atomicAdd(o + 1, v * bfhi(s.x));
  atomicAdd(o + 2, v * bflo(s.y));
  atomicAdd(o + 3, v * bfhi(s.y));
}

extern "C" void kernel_launch(void* const* d_in, const int* in_sizes, int n_in,
                              void* d_out, int out_size, void* d_ws, size_t ws_size,
                              hipStream_t stream) {
  const float* x        = (const float*)d_in[0];
  const float* W        = (const float*)d_in[1];
  const float* lin_bias = (const float*)d_in[2];
  const float* bias     = (const float*)d_in[3];
  const int*   adj_rows = (const int*)d_in[4];
  const int*   adj_cols = (const int*)d_in[5];
  const float* adj_vals = (const float*)d_in[6];
  float* out = (float*)d_out;

  // Workspace layout (16B-aligned offsets):
  //   support   : 25,600,000 B  (N_NODES*D bf16)
  //   row_start :    400,016 B  (SCAN_N ints, padded)
  //   count/gofs:  3,200,000 B  (N_NODES*8 ints)
  //   rank      :  1,600,000 B  (N_EDGES u8)
  //   pairs     :  6,400,000 B  (N_EDGES u32, packed col|q15)
  //   partials  :        512 B
  char* wsb = (char*)d_ws;
  unsigned short* support   = (unsigned short*)wsb;
  int*            row_start = (int*)(wsb + 25600000);
  int*            count     = (int*)(wsb + 26000016);
  unsigned char*  rank      = (unsigned char*)(wsb + 29200016);
  unsigned*       pairs     = (unsigned*)(wsb + 30800016);
  int*            partials  = (int*)(wsb + 37200016);
  const size_t ws_needed = 37200528;

  gemm_kernel<<<(N_NODES + GR - 1) / GR, 256, 0, stream>>>(x, W, lin_bias,
                                                           support);

  if (ws_size >= ws_needed) {
    zero_kernel<<<(N_NODES * NGROUP) / 256, 256, 0, stream>>>(count,
                                                              N_NODES * NGROUP);
    hist_kernel<<<N_EDGES / 256, 256, 0, stream>>>(adj_rows, count, rank);
    scan1_kernel<<<SCAN_BLOCKS, 1024, 0, stream>>>(count, row_start, partials);
    scan2_kernel<<<1, 128, 0, stream>>>(partials);
    scan3_kernel<<<SCAN_BLOCKS, 1024, 0, stream>>>(row_start, partials, count);
    build_kernel<<<N_EDGES / 256, 256, 0, stream>>>(adj_rows, adj_cols,
                                                    adj_vals, count, rank,
                                                    pairs);
    gather_kernel<<<N_NODES / 4, 256, 0, stream>>>(row_start, pairs,
                                                   (const unsigned*)support,
                                                   bias, out);
  } else {
    init_out_kernel<<<12500, 256, 0, stream>>>(bias, out);
    scatter_kernel<<<200000, 256, 0, stream>>>(adj_rows, adj_cols, adj_vals,
                                               (const unsigned*)support, out);
  }
}